// Round 2
// baseline (499.126 us; speedup 1.0000x reference)
//
#include <hip/hip_runtime.h>
#include <hip/hip_bf16.h>
#include <math.h>

typedef __attribute__((ext_vector_type(8))) short bf16x8;
typedef __attribute__((ext_vector_type(4))) float f32x4;

#define EPW 8      // edges per wave
#define WAVES 4    // waves per block (256 threads)
#define XS 40      // staged image row stride in ushorts per pixel (80B, 16B-aligned)
#define WST 296    // staged weight row stride in ushorts per co (592B, 16B-aligned)

__device__ __forceinline__ unsigned short bf16bits(float f) {
    union { __hip_bfloat16 h; unsigned short u; } cv;
    cv.h = __float2bfloat16(f);
    return cv.u;
}

// Stage one [32ci][64pix] fp32 image into LDS as bf16 transposed [pix][ci], stride XS.
__device__ __forceinline__ void stage_img(const float* __restrict__ g,
                                          unsigned short* xw, int lane) {
    #pragma unroll
    for (int i = 0; i < 16; ++i) {
        float v0 = g[(2 * i) * 64 + lane];        // coalesced: lane = pixel
        float v1 = g[(2 * i + 1) * 64 + lane];
        unsigned int pk = (unsigned int)bf16bits(v0) |
                          ((unsigned int)bf16bits(v1) << 16);
        *(unsigned int*)&xw[lane * XS + 2 * i] = pk;   // x_t[pix=lane][ci pair 2i,2i+1]
    }
}

// One 3x3 conv as GEMM: C[32co x 64pix] = W[32 x 288] * im2col[288 x 64].
// K ordered (kh,kw)-major: K-block kb (K=32) = filter tap (kh,kw) across all 32 ci.
__device__ __forceinline__ void conv_mfma(const unsigned short* __restrict__ xw,
                                          const unsigned short* __restrict__ wl,
                                          int m, int quad, f32x4 acc[2][4]) {
    #pragma unroll
    for (int kb = 0; kb < 9; ++kb) {
        const int kh = kb / 3, kw = kb - kh * 3;
        // A-frag: lane holds W[m(+16*mt)][kb*32 + quad*8 + j], j=0..7 contiguous bf16
        bf16x8 a0 = *(const bf16x8*)&wl[ m        * WST + kb * 32 + quad * 8];
        bf16x8 a1 = *(const bf16x8*)&wl[(m + 16)  * WST + kb * 32 + quad * 8];
        #pragma unroll
        for (int nt = 0; nt < 4; ++nt) {
            const int p  = nt * 16 + m;            // output pixel for this lane
            const int ih = (p >> 3) + kh - 1;      // padded input row
            const int iw = (p & 7) + kw - 1;       // padded input col
            const bool valid = ((unsigned)ih < 8u) && ((unsigned)iw < 8u);
            const int pixp = valid ? (ih * 8 + iw) : 0;
            // B-frag: lane holds X[ci = quad*8 + j][pixel p] = x_t[pixp][quad*8+j]
            bf16x8 b = *(const bf16x8*)&xw[pixp * XS + quad * 8];
            if (!valid) b = (bf16x8)(short)0;      // zero-padding tap -> zero fragment
            acc[0][nt] = __builtin_amdgcn_mfma_f32_16x16x32_bf16(a0, b, acc[0][nt], 0, 0, 0);
            acc[1][nt] = __builtin_amdgcn_mfma_f32_16x16x32_bf16(a1, b, acc[1][nt], 0, 0, 0);
        }
    }
}

__global__ __launch_bounds__(256, 2)
void fused_edge_kernel(const float* __restrict__ input,
                       const int* __restrict__ srcv,
                       const float* __restrict__ e,
                       const float* __restrict__ w_node,
                       const float* __restrict__ w_edge,
                       float* __restrict__ out,
                       int n_edges)
{
    __shared__ __align__(16) unsigned short w_lds[2][32 * WST];   // [0]=w_edge [1]=w_node, ~37.9 KB
    __shared__ __align__(16) unsigned short x_lds[WAVES][64 * XS]; // per-wave image, 20 KB

    const int t = threadIdx.x;
    const int lane = t & 63;
    const int wave = t >> 6;

    // Stage both weight tensors: fp32 OIHW -> bf16 [co][(kh*3+kw)*32 + ci]
    for (int i = t; i < 9216; i += 256) {
        int co  = i / 288;
        int rem = i - co * 288;
        int ci  = rem / 9;
        int khw = rem - ci * 9;
        int dst = co * WST + khw * 32 + ci;
        w_lds[0][dst] = bf16bits(w_edge[i]);
        w_lds[1][dst] = bf16bits(w_node[i]);
    }
    __syncthreads();  // only barrier; everything after is wave-private

    const int m    = lane & 15;
    const int quad = lane >> 4;
    unsigned short* xw = x_lds[wave];

    const int img0 = (blockIdx.x * WAVES + wave) * EPW;

    for (int j = 0; j < EPW; ++j) {
        const int img = img0 + j;
        if (img >= n_edges) break;   // wave-uniform

        f32x4 accz[2][4], acct[2][4];
        #pragma unroll
        for (int a = 0; a < 2; ++a)
            #pragma unroll
            for (int b = 0; b < 4; ++b) { accz[a][b] = (f32x4)0.f; acct[a][b] = (f32x4)0.f; }

        // z = conv3x3(e[img], w_edge)
        stage_img(e + (size_t)img * 2048, xw, lane);
        conv_mfma(xw, w_lds[0], m, quad, accz);

        // th = conv3x3(input[src[img]], w_node)  (recomputed per edge -> no workspace)
        stage_img(input + (size_t)srcv[img] * 2048, xw, lane);
        conv_mfma(xw, w_lds[1], m, quad, acct);

        // out = elu(th * z); C/D layout: row(co) = quad*4 + r (+16*mt), col(pix) = m (+16*nt)
        float* op = out + (size_t)img * 2048;
        #pragma unroll
        for (int mt = 0; mt < 2; ++mt)
            #pragma unroll
            for (int nt = 0; nt < 4; ++nt)
                #pragma unroll
                for (int r = 0; r < 4; ++r) {
                    const int co = mt * 16 + quad * 4 + r;
                    const int p  = nt * 16 + m;
                    float v = accz[mt][nt][r] * acct[mt][nt][r];
                    op[co * 64 + p] = v > 0.f ? v : (__expf(v) - 1.f);
                }
    }
}

extern "C" void kernel_launch(void* const* d_in, const int* in_sizes, int n_in,
                              void* d_out, int out_size, void* d_ws, size_t ws_size,
                              hipStream_t stream)
{
    // setup_inputs order: input, edge_sources, e, w_node, w_edge
    const float* input        = (const float*)d_in[0];
    const int*   edge_sources = (const int*)  d_in[1];
    const float* e            = (const float*)d_in[2];
    const float* w_node       = (const float*)d_in[3];
    const float* w_edge       = (const float*)d_in[4];
    float* out = (float*)d_out;
    (void)d_ws; (void)ws_size;   // deliberately unused: R1 post-timing divergence
                                 // implicates d_ws overrun corrupting pristine inputs

    const int n_edges = in_sizes[1];                       // 32768
    const int per_block = WAVES * EPW;                     // 32 edges per block
    const int grid = (n_edges + per_block - 1) / per_block;

    fused_edge_kernel<<<dim3(grid), dim3(256), 0, stream>>>(
        input, edge_sources, e, w_node, w_edge, out, n_edges);
}